// Round 3
// baseline (1383.756 us; speedup 1.0000x reference)
//
#include <hip/hip_runtime.h>

// Correlation / cost volume:
// corr[n, dy*9+dx, h, w] = sum_c f0[n,c,h,w] * f1[n,c,h+dy-4,w+dx-4] (0-padded)
// N=8, C=256, H=W=128, MAX_DISP=4 -> D=9, 81 disp channels.
//
// Block = 576 threads = 9 waves; wave w handles dy=w. Lane -> (ty 0..31, tx 0..1).
// Tile: 32 rows x 16 cols of output pixels; thread computes 8 px x 9 dx = 72 accs.
// fmap1 halo tile (40 rows x 24 cols, padded stride 36) double-buffered in LDS.
//
// LDS = 2*8*40*36*4 = 92160 B  > 80 KB  =>  1 block/CU  =>  backend's implied
// occupancy = floor(9 waves / 4 SIMD) = 2 waves/EU  =>  VGPR cap ~170-256.
// (R1/R2 failure: 40 KB LDS -> 3 blocks/CU -> 6 waves/EU -> cap 84 -> the 72-
// element accumulator spilled to scratch: 1.6 GB writes, VALUBusy 4.4%.
// launch_bounds' 2nd arg cannot lower the implied minimum -- LDS size can.)

#define CCH 8        // channels per LDS chunk
#define TH  32       // tile rows
#define TWp 16       // tile cols
#define PX  8        // pixels per thread (along w)
#define DD  9        // displacement count per axis
#define HR  40       // halo rows  = TH + 8
#define LSTR 36      // LDS row stride in floats (144 B, padded: breaks bank alignment)
#define Cc  256
#define Hh  128
#define Ww  128

__global__ __launch_bounds__(576)
void corr_kernel(const float* __restrict__ f0,
                 const float* __restrict__ f1,
                 float* __restrict__ out) {
    const int tid  = threadIdx.x;
    const int wave = tid >> 6;        // dy in [0,9)
    const int lane = tid & 63;
    const int ty   = lane >> 1;       // 0..31 (output row within tile)
    const int tx   = lane & 1;        // 0..1  (8-px group)

    const int bid = blockIdx.x;
    const int n   = bid >> 5;         // 8 images
    const int hb  = (bid >> 3) & 3;   // 4 h-tiles
    const int wb  = bid & 7;          // 8 w-tiles
    const int h0  = hb * TH;
    const int w0  = wb * TWp;

    __shared__ float lds[2][CCH][HR][LSTR];   // 92160 B (double buffer)

    // staging decomposition: 576 threads = 24 j x 24 r-slots (x2 row passes)
    const int sj  = tid % 24;              // halo col
    const int srq = tid / 24;              // base halo row slot

    const float* f1n    = f1 + (size_t)n * Cc * Hh * Ww;
    const float* f0base = f0 + ((size_t)(n * Cc) * Hh + (h0 + ty)) * Ww + w0 + PX * tx;

    float acc[DD][PX];
#pragma unroll
    for (int d = 0; d < DD; ++d)
#pragma unroll
        for (int p = 0; p < PX; ++p) acc[d][p] = 0.f;

    // loop-invariant staging geometry
    const int  r0   = srq;             // 0..23
    const int  r1   = srq + 24;        // 24..47 (valid when < HR)
    const int  gh_a = h0 - 4 + r0;
    const int  gh_b = h0 - 4 + r1;
    const int  gw   = w0 - 4 + sj;
    const bool wok  = ((unsigned)gw < (unsigned)Ww);
    const bool ok_a = ((unsigned)gh_a < (unsigned)Hh) && wok;
    const bool ok_b = (r1 < HR) && ((unsigned)gh_b < (unsigned)Hh) && wok;
    const long off_a = (long)gh_a * Ww + gw;
    const long off_b = (long)gh_b * Ww + gw;

    float stg[CCH][2];

#define LOAD_CHUNK(C0)                                                         \
    {                                                                          \
        _Pragma("unroll")                                                      \
        for (int c = 0; c < CCH; ++c) {                                        \
            const float* base = f1n + (size_t)((C0) + c) * (Hh * Ww);          \
            stg[c][0] = ok_a ? base[off_a] : 0.f;                              \
            stg[c][1] = ok_b ? base[off_b] : 0.f;                              \
        }                                                                      \
    }

#define STORE_CHUNK(B)                                                         \
    {                                                                          \
        _Pragma("unroll")                                                      \
        for (int c = 0; c < CCH; ++c) {                                        \
            lds[B][c][r0][sj] = stg[c][0];                                     \
            if (r1 < HR) lds[B][c][r1][sj] = stg[c][1];                        \
        }                                                                      \
    }

    // prologue
    LOAD_CHUNK(0);
    STORE_CHUNK(0);
    __syncthreads();

    const int NCHUNK = Cc / CCH;   // 32
    const int row = ty + wave;     // halo row this wave reads (0..39)
    for (int k = 0; k < NCHUNK; ++k) {
        const int buf = k & 1;
        const bool more = (k + 1 < NCHUNK);
        if (more) LOAD_CHUNK((k + 1) * CCH);   // issue next-chunk loads early

        const int c0 = k * CCH;
#pragma unroll
        for (int cc = 0; cc < CCH; ++cc) {
            const float* fp = f0base + (size_t)(c0 + cc) * (Hh * Ww);
            const float4 a0 = *reinterpret_cast<const float4*>(fp);
            const float4 a1 = *reinterpret_cast<const float4*>(fp + 4);
            const float a[PX] = {a0.x, a0.y, a0.z, a0.w, a1.x, a1.y, a1.z, a1.w};

            // 16-float window starting at halo col 8*tx (16B-aligned: 144B rows)
            const float4* wrow =
                reinterpret_cast<const float4*>(&lds[buf][cc][row][0]) + 2 * tx;
            float wv[16];
#pragma unroll
            for (int i = 0; i < 4; ++i) {
                const float4 v = wrow[i];
                wv[4 * i + 0] = v.x;
                wv[4 * i + 1] = v.y;
                wv[4 * i + 2] = v.z;
                wv[4 * i + 3] = v.w;
            }
#pragma unroll
            for (int dx = 0; dx < DD; ++dx)
#pragma unroll
                for (int p = 0; p < PX; ++p)
                    acc[dx][p] += a[p] * wv[p + dx];
        }

        if (more) {
            STORE_CHUNK(buf ^ 1);   // write NEXT buffer: no collision with readers of buf
            __syncthreads();        // single barrier per iteration
        }
    }

    // epilogue: write 72 outputs per thread (2x float4 per dx)
    const int hh  = h0 + ty;
    const int wwp = w0 + PX * tx;
#pragma unroll
    for (int dx = 0; dx < DD; ++dx) {
        const int d = wave * DD + dx;
        float* op = out + (((size_t)n * (DD * DD) + d) * Hh + hh) * Ww + wwp;
        const float4 o0 = make_float4(acc[dx][0], acc[dx][1], acc[dx][2], acc[dx][3]);
        const float4 o1 = make_float4(acc[dx][4], acc[dx][5], acc[dx][6], acc[dx][7]);
        *reinterpret_cast<float4*>(op)     = o0;
        *reinterpret_cast<float4*>(op + 4) = o1;
    }
}

extern "C" void kernel_launch(void* const* d_in, const int* in_sizes, int n_in,
                              void* d_out, int out_size, void* d_ws, size_t ws_size,
                              hipStream_t stream) {
    const float* f0 = (const float*)d_in[0];
    const float* f1 = (const float*)d_in[1];
    float* out = (float*)d_out;
    // grid: 8 n * 4 h-tiles * 8 w-tiles = 256 blocks, 576 threads
    corr_kernel<<<dim3(256), dim3(576), 0, stream>>>(f0, f1, out);
}

// Round 4
// 169.215 us; speedup vs baseline: 8.1775x; 8.1775x over previous
//
#include <hip/hip_runtime.h>

// Correlation / cost volume:
// corr[n, dy*9+dx, h, w] = sum_c f0[n,c,h,w] * f1[n,c,h+dy-4,w+dx-4] (0-padded)
// N=8, C=256, H=W=128, MAX_DISP=4 -> D=9, 81 disp channels.
//
// R1-R3 lesson: compiler pins VGPR budget at 84 (spilled 72-float acc ->
// 1.6-3.1 GB scratch traffic, VALUBusy <5%). Fix: design UNDER 84 VGPRs.
//   - PX=4: acc = float4[9] = 36 regs; window 12; staging 8; f0 4; addrs ~15.
//   - tile 16x16, 9 waves (wave = dy), lane -> (ty=lane>>2, tx=lane&3).
//   - grid 8n x 8hb x 8wb = 512 blocks = 2/CU -> 18 waves/CU TLP.
// LDS: halo 24x24 per channel-chunk (CCH=8), double-buffered = 48 KB.
// Banking: row stride 32 floats, additive skew 2 units/row: physical 16B-unit
//   u_phys = (u_log + 2*row) & 7. Quarter-wave (ty 0..3 x tx 0..3) b128 reads
//   hit each 4-bank group exactly 2x (2-way is free). Skew indices are
//   thread-invariant -> hoisted before the k-loop.

#define CCH 8        // channels per LDS chunk
#define TH  16       // tile rows
#define TWp 16       // tile cols
#define DD  9        // displacements per axis
#define HR  24       // halo rows
#define Cc  256
#define Hh  128
#define Ww  128

__global__ __attribute__((amdgpu_waves_per_eu(2, 8))) __launch_bounds__(576)
void corr_kernel(const float* __restrict__ f0,
                 const float* __restrict__ f1,
                 float* __restrict__ out) {
    const int tid  = threadIdx.x;
    const int wave = tid >> 6;        // dy in [0,9)
    const int lane = tid & 63;
    const int ty   = lane >> 2;       // 0..15 (output row within tile)
    const int tx   = lane & 3;        // 0..3  (4-px group)

    const int bid = blockIdx.x;
    const int n   = bid >> 6;         // 8 images
    const int hb  = (bid >> 3) & 7;   // 8 h-tiles
    const int wb  = bid & 7;          // 8 w-tiles
    const int h0  = hb * TH;
    const int w0  = wb * TWp;

    __shared__ float4 lds4[2][CCH][HR][8];   // 49152 B
    float* const       ldsf  = (float*)lds4;
    const float4* const lds4f = (const float4*)lds4;

    // ---- staging geometry: 576 threads = 24 rows x 24 cols, 1 elem/channel
    const int sr = tid / 24;               // halo row 0..23
    const int sc = tid % 24;               // halo col 0..23
    const int gh = h0 - 4 + sr;
    const int gw = w0 - 4 + sc;
    const bool ok = ((unsigned)gh < (unsigned)Hh) && ((unsigned)gw < (unsigned)Ww);
    const size_t g_off = (size_t)gh * Ww + gw;
    // swizzled write slot (floats) within one [HR][8xfloat4] channel block
    const int wslot = sr * 32 + 4 * (((sc >> 2) + 2 * sr) & 7) + (sc & 3);

    const float* f1n    = f1 + (size_t)n * Cc * Hh * Ww;
    const float* f0base = f0 + (((size_t)n * Cc) * Hh + (h0 + ty)) * Ww + w0 + 4 * tx;

    // ---- read geometry (thread-invariant)
    const int row  = ty + wave;            // halo row this thread reads, 0..23
    const int rb   = row * 8;              // float4 index of row base
    const int ri0  = rb + ((tx + 0 + 2 * row) & 7);
    const int ri1  = rb + ((tx + 1 + 2 * row) & 7);
    const int ri2  = rb + ((tx + 2 + 2 * row) & 7);

    float4 acc[DD];
#pragma unroll
    for (int d = 0; d < DD; ++d) acc[d] = make_float4(0.f, 0.f, 0.f, 0.f);

    float stg[CCH];

#define LOAD_CHUNK(C0)                                                         \
    {                                                                          \
        _Pragma("unroll")                                                      \
        for (int c = 0; c < CCH; ++c)                                          \
            stg[c] = ok ? f1n[(size_t)((C0) + c) * (Hh * Ww) + g_off] : 0.f;   \
    }

#define STORE_CHUNK(B)                                                         \
    {                                                                          \
        _Pragma("unroll")                                                      \
        for (int c = 0; c < CCH; ++c)                                          \
            ldsf[(B) * (CCH * HR * 32) + c * (HR * 32) + wslot] = stg[c];      \
    }

    LOAD_CHUNK(0);
    STORE_CHUNK(0);
    __syncthreads();

    const int NCHUNK = Cc / CCH;   // 32
    for (int k = 0; k < NCHUNK; ++k) {
        const int buf = k & 1;
        if (k + 1 < NCHUNK) LOAD_CHUNK((k + 1) * CCH);   // issue next loads early

        const int c0 = k * CCH;
#pragma unroll
        for (int cc = 0; cc < CCH; ++cc) {
            const float4 a =
                *reinterpret_cast<const float4*>(f0base + (size_t)(c0 + cc) * (Hh * Ww));
            const int cb = buf * (CCH * HR * 8) + cc * (HR * 8);
            const float4 q0 = lds4f[cb + ri0];
            const float4 q1 = lds4f[cb + ri1];
            const float4 q2 = lds4f[cb + ri2];
            const float w[12] = {q0.x, q0.y, q0.z, q0.w,
                                 q1.x, q1.y, q1.z, q1.w,
                                 q2.x, q2.y, q2.z, q2.w};
#pragma unroll
            for (int dx = 0; dx < DD; ++dx) {
                acc[dx].x += a.x * w[dx + 0];
                acc[dx].y += a.y * w[dx + 1];
                acc[dx].z += a.z * w[dx + 2];
                acc[dx].w += a.w * w[dx + 3];
            }
        }

        if (k + 1 < NCHUNK) {
            STORE_CHUNK(buf ^ 1);   // write the buffer nobody is reading
            __syncthreads();
        }
    }

    // ---- epilogue: 9 float4 stores per thread
    const int hh  = h0 + ty;
    const int wwp = w0 + 4 * tx;
#pragma unroll
    for (int dx = 0; dx < DD; ++dx) {
        const int d = wave * DD + dx;
        float* op = out + (((size_t)n * (DD * DD) + d) * Hh + hh) * Ww + wwp;
        *reinterpret_cast<float4*>(op) = acc[dx];
    }
}

extern "C" void kernel_launch(void* const* d_in, const int* in_sizes, int n_in,
                              void* d_out, int out_size, void* d_ws, size_t ws_size,
                              hipStream_t stream) {
    const float* f0 = (const float*)d_in[0];
    const float* f1 = (const float*)d_in[1];
    float* out = (float*)d_out;
    // grid: 8 n * 8 h-tiles * 8 w-tiles = 512 blocks, 576 threads
    corr_kernel<<<dim3(512), dim3(576), 0, stream>>>(f0, f1, out);
}